// Round 5
// baseline (581.844 us; speedup 1.0000x reference)
//
#include <hip/hip_runtime.h>
#include <stdint.h>

#define N_NODES 50000
#define N_EDGES 800000
#define IN_CH   512
#define HID_CH  256
#define OUT_CH  128
#define NPAD    50048
#define SLOT    96      // padded CSR slots/node; P(Poisson(16) > 96) ~ 0
#define MTILES  391     // ceil(50000/128)

// mega-prep block ranges (2048 elems per block)
#define PB_X   12500    // x split: 12500*2048 = 25.6M
#define PB_W0  12564    // W0: 64 blocks (131072)
#define PB_W1  12580    // W1: 16 blocks (32768)
#define PB_PW  12588    // PW: 8 blocks (16384)
#define PB_E   15713    // bucket: 3125 blocks (800000)

typedef unsigned short ushort_t;
typedef __attribute__((ext_vector_type(8))) short    short8;  // 8 bf16 (MFMA A/B frag)
typedef __attribute__((ext_vector_type(4))) float    floatx4; // MFMA C/D frag
typedef __attribute__((ext_vector_type(2))) _Float16 half2v;  // 4B gather chunk

__device__ inline ushort_t f2bf(float x) {                  // fp32 -> bf16 RNE
    union { float f; unsigned u; } v; v.f = x;
    unsigned r = v.u + 0x7fffu + ((v.u >> 16) & 1u);
    return (ushort_t)(r >> 16);
}
__device__ inline float bf2f(ushort_t h) {
    union { unsigned u; float f; } v; v.u = ((unsigned)h) << 16;
    return v.f;
}
__device__ inline void gl_lds16(const void* g, void* l) {   // async global->LDS, 16B/lane
    __builtin_amdgcn_global_load_lds((const __attribute__((address_space(1))) void*)g,
                                     (__attribute__((address_space(3))) void*)l, 16, 0, 0);
}

// ---------------- mega prep: x split + weight split/transpose + edge bucketing ---------
__device__ inline void conv_splitT8(const float* __restrict__ W,
                                    ushort_t* __restrict__ WhT,
                                    ushort_t* __restrict__ WlT,
                                    int K, int N, int base) {
    float4 v0 = *(const float4*)(W + base);
    float4 v1 = *(const float4*)(W + base + 4);
    float vv[8] = {v0.x, v0.y, v0.z, v0.w, v1.x, v1.y, v1.z, v1.w};
    #pragma unroll
    for (int j = 0; j < 8; ++j) {
        int g = base + j;
        int k = g / N, n = g - k * N;
        ushort_t h = f2bf(vv[j]);
        WhT[(size_t)n * K + k] = h;
        WlT[(size_t)n * K + k] = f2bf(vv[j] - bf2f(h));
    }
}

__global__ __launch_bounds__(256) void k_prep(const float* __restrict__ x,
                                              const float* __restrict__ W0,
                                              const float* __restrict__ W1,
                                              const float* __restrict__ PW,
                                              const int* __restrict__ esrc,
                                              const int* __restrict__ edst,
                                              ushort_t* __restrict__ xh,
                                              ushort_t* __restrict__ xl,
                                              int* __restrict__ cnt,       // pre-zeroed
                                              int* __restrict__ slots,
                                              ushort_t* W0hT, ushort_t* W0lT,
                                              ushort_t* W1hT, ushort_t* W1lT,
                                              ushort_t* PWhT, ushort_t* PWlT) {
    int b = blockIdx.x, tid = threadIdx.x;
    if (b < PB_X) {                                        // x -> split bf16 (coalesced)
        int g = b * 2048 + tid * 8;
        float4 v0 = *(const float4*)(x + g);
        float4 v1 = *(const float4*)(x + g + 4);
        float vv[8] = {v0.x, v0.y, v0.z, v0.w, v1.x, v1.y, v1.z, v1.w};
        ushort_t hh[8], ll[8];
        #pragma unroll
        for (int j = 0; j < 8; ++j) {
            hh[j] = f2bf(vv[j]);
            ll[j] = f2bf(vv[j] - bf2f(hh[j]));
        }
        *(ushort4*)(xh + g)     = make_ushort4(hh[0], hh[1], hh[2], hh[3]);
        *(ushort4*)(xh + g + 4) = make_ushort4(hh[4], hh[5], hh[6], hh[7]);
        *(ushort4*)(xl + g)     = make_ushort4(ll[0], ll[1], ll[2], ll[3]);
        *(ushort4*)(xl + g + 4) = make_ushort4(ll[4], ll[5], ll[6], ll[7]);
    } else if (b < PB_W0) {
        conv_splitT8(W0, W0hT, W0lT, IN_CH, HID_CH, (b - PB_X) * 2048 + tid * 8);
    } else if (b < PB_W1) {
        conv_splitT8(W1, W1hT, W1lT, HID_CH, OUT_CH, (b - PB_W0) * 2048 + tid * 8);
    } else if (b < PB_PW) {
        conv_splitT8(PW, PWhT, PWlT, OUT_CH, OUT_CH, (b - PB_W1) * 2048 + tid * 8);
    } else {                                               // edge bucketing (3125*256 = 800000)
        int e = (b - PB_PW) * 256 + tid;
        int d = edst[e];
        int c = atomicAdd(&cnt[d], 1);
        slots[(size_t)d * SLOT + c] = esrc[e];
    }
}

// =====================================================================
// split-bf16 MFMA GEMM, C[M,N] = A[M,K] @ B[K,N]  (A as Ah/Al [M][K], B as BhT/BlT [N][K])
// 128x128 tile, BK=32, 256 threads = 4 waves, each wave 64x64 (4x4 16x16 tiles)
// 3 MFMAs per frag pair: Ah*Bh + Ah*Bl + Al*Bh  (~fp32 precision, Al*Bl dropped)
// MODE 0: plain C[row*N+col]   MODE 1: half-split C[(n0>>7)][row][128] (N=256 table)
// MODE 2: no C write; fused column max/argmax -> pv/pi[blockIdx.y*128 + col]
// =====================================================================
template <typename OUT, int MODE>
__global__ __launch_bounds__(256) void gemm_bf(const ushort_t* __restrict__ Ah,
                                               const ushort_t* __restrict__ Al,
                                               const ushort_t* __restrict__ BhT,
                                               const ushort_t* __restrict__ BlT,
                                               OUT* __restrict__ C,
                                               float* __restrict__ pv,
                                               int* __restrict__ pi,
                                               int M, int N, int K) {
    __shared__ ushort_t sm[4][128 * 32];
    const int tid  = threadIdx.x;
    const int wave = tid >> 6, lane = tid & 63;
    const int m0 = blockIdx.y * 128, n0 = blockIdx.x * 128;

    const int c0 = wave * 128 + lane, c1 = c0 + 64;
    const int ar0 = min(m0 + (c0 >> 2), M - 1), ar1 = min(m0 + (c1 >> 2), M - 1);
    const ushort_t* gah0 = Ah + (size_t)ar0 * K + (c0 & 3) * 8;
    const ushort_t* gah1 = Ah + (size_t)ar1 * K + (c1 & 3) * 8;
    const ushort_t* gal0 = Al + (size_t)ar0 * K + (c0 & 3) * 8;
    const ushort_t* gal1 = Al + (size_t)ar1 * K + (c1 & 3) * 8;
    const ushort_t* gbh0 = BhT + (size_t)(n0 + (c0 >> 2)) * K + (c0 & 3) * 8;
    const ushort_t* gbh1 = BhT + (size_t)(n0 + (c1 >> 2)) * K + (c1 & 3) * 8;
    const ushort_t* gbl0 = BlT + (size_t)(n0 + (c0 >> 2)) * K + (c0 & 3) * 8;
    const ushort_t* gbl1 = BlT + (size_t)(n0 + (c1 >> 2)) * K + (c1 & 3) * 8;
    ushort_t* la0 = &sm[0][wave * 1024];       ushort_t* la1 = &sm[0][wave * 1024 + 512];
    ushort_t* ll0 = &sm[1][wave * 1024];       ushort_t* ll1 = &sm[1][wave * 1024 + 512];
    ushort_t* lb0 = &sm[2][wave * 1024];       ushort_t* lb1 = &sm[2][wave * 1024 + 512];
    ushort_t* lc0 = &sm[3][wave * 1024];       ushort_t* lc1 = &sm[3][wave * 1024 + 512];

    floatx4 zero = {0.f, 0.f, 0.f, 0.f};
    floatx4 acc[4][4];
    #pragma unroll
    for (int i = 0; i < 4; ++i)
        #pragma unroll
        for (int j = 0; j < 4; ++j) acc[i][j] = zero;

    const int wm = (wave & 1) * 64, wn = (wave >> 1) * 64;
    const int fr = lane & 15, fq = lane >> 4;

    for (int k0 = 0; k0 < K; k0 += 32) {
        gl_lds16(gah0, la0); gl_lds16(gah1, la1);
        gl_lds16(gal0, ll0); gl_lds16(gal1, ll1);
        gl_lds16(gbh0, lb0); gl_lds16(gbh1, lb1);
        gl_lds16(gbl0, lc0); gl_lds16(gbl1, lc1);
        gah0 += 32; gah1 += 32; gal0 += 32; gal1 += 32;
        gbh0 += 32; gbh1 += 32; gbl0 += 32; gbl1 += 32;
        __syncthreads();
        short8 afh[4], afl[4], bfh[4], bfl[4];
        #pragma unroll
        for (int t = 0; t < 4; ++t) {
            int ai = (wm + t * 16 + fr) * 32 + fq * 8;
            int bi = (wn + t * 16 + fr) * 32 + fq * 8;
            afh[t] = *(const short8*)&sm[0][ai];
            afl[t] = *(const short8*)&sm[1][ai];
            bfh[t] = *(const short8*)&sm[2][bi];
            bfl[t] = *(const short8*)&sm[3][bi];
        }
        #pragma unroll
        for (int i = 0; i < 4; ++i)
            #pragma unroll
            for (int j = 0; j < 4; ++j) {
                acc[i][j] = __builtin_amdgcn_mfma_f32_16x16x32_bf16(afh[i], bfh[j], acc[i][j], 0, 0, 0);
                acc[i][j] = __builtin_amdgcn_mfma_f32_16x16x32_bf16(afh[i], bfl[j], acc[i][j], 0, 0, 0);
                acc[i][j] = __builtin_amdgcn_mfma_f32_16x16x32_bf16(afl[i], bfh[j], acc[i][j], 0, 0, 0);
            }
        __syncthreads();
    }

    if constexpr (MODE == 2) {
        // fused column max/argmax; ties -> lowest row index (matches jnp.argmax)
        float bv[4]; int bix[4];
        #pragma unroll
        for (int j = 0; j < 4; ++j) { bv[j] = -3.402823466e+38f; bix[j] = 0x7fffffff; }
        #pragma unroll
        for (int i = 0; i < 4; ++i)
            #pragma unroll
            for (int r = 0; r < 4; ++r) {
                int row = m0 + wm + i * 16 + fq * 4 + r;
                bool ok = row < M;
                #pragma unroll
                for (int j = 0; j < 4; ++j) {
                    float v = ok ? acc[i][j][r] : -3.402823466e+38f;
                    if (v > bv[j] || (v == bv[j] && row < bix[j])) { bv[j] = v; bix[j] = row; }
                }
            }
        #pragma unroll
        for (int off = 16; off <= 32; off <<= 1)
            #pragma unroll
            for (int j = 0; j < 4; ++j) {
                float ov = __shfl_xor(bv[j], off);
                int   oi = __shfl_xor(bix[j], off);
                if (ov > bv[j] || (ov == bv[j] && oi < bix[j])) { bv[j] = ov; bix[j] = oi; }
            }
        __shared__ float redv[4][64];
        __shared__ int   redi[4][64];
        if (fq == 0) {
            #pragma unroll
            for (int j = 0; j < 4; ++j) {
                redv[wave][fr + 16 * j] = bv[j];
                redi[wave][fr + 16 * j] = bix[j];
            }
        }
        __syncthreads();
        if (tid < 128) {
            int col = tid, c64 = col & 63;
            int w0 = (col < 64) ? 0 : 2;                   // waves {0,1}: cols 0-63; {2,3}: 64-127
            float v0 = redv[w0][c64], v1 = redv[w0 + 1][c64];
            int   i0 = redi[w0][c64], i1 = redi[w0 + 1][c64];
            if (v1 > v0 || (v1 == v0 && i1 < i0)) { v0 = v1; i0 = i1; }
            pv[blockIdx.y * 128 + col] = v0;
            pi[blockIdx.y * 128 + col] = i0;
        }
    } else {
        const int colb = n0 + wn + fr;
        #pragma unroll
        for (int i = 0; i < 4; ++i) {
            int rowb = m0 + wm + i * 16 + fq * 4;
            #pragma unroll
            for (int r = 0; r < 4; ++r) {
                int row = rowb + r;
                if (row < M) {
                    OUT* cp;
                    if constexpr (MODE == 1)
                        cp = C + (size_t)(n0 >> 7) * NPAD * 128 + (size_t)row * 128 + (wn + fr);
                    else
                        cp = C + (size_t)row * N + colb;
                    cp[0]  = (OUT)acc[i][0][r];
                    cp[16] = (OUT)acc[i][1][r];
                    cp[32] = (OUT)acc[i][2][r];
                    cp[48] = (OUT)acc[i][3][r];
                }
            }
        }
    }
}

// ------- aggregation layer 0: table [2][NPAD][128] fp16, 2 col-half phases ------------
__global__ __launch_bounds__(256) void agg256_relu_bf(const _Float16* __restrict__ hl,
                                                      const int* __restrict__ cnt,
                                                      const int* __restrict__ slots,
                                                      const float* __restrict__ bias,
                                                      ushort_t* __restrict__ oh,
                                                      ushort_t* __restrict__ ol) {
    int d = blockIdx.x * 4 + (threadIdx.x >> 6);
    int lane = threadIdx.x & 63;
    int n = cnt[d];
    float di = rsqrtf((float)n + 1.0f);                    // +1 self loop
    const int* sl = slots + (size_t)d * SLOT;
    #pragma unroll
    for (int half = 0; half < 2; ++half) {
        const _Float16* tab = hl + (size_t)half * NPAD * 128;
        half2v v = ((const half2v*)(tab + (size_t)d * 128))[lane];
        float w = di * di;
        float ax = w * (float)v[0], ay = w * (float)v[1];
        int e = 0;
        for (; e + 8 <= n; e += 8) {
            int s[8]; half2v u[8]; float ws[8];
            #pragma unroll
            for (int j = 0; j < 8; ++j) s[j] = sl[e + j];
            #pragma unroll
            for (int j = 0; j < 8; ++j) u[j] = ((const half2v*)(tab + (size_t)s[j] * 128))[lane];
            #pragma unroll
            for (int j = 0; j < 8; ++j) ws[j] = rsqrtf((float)cnt[s[j]] + 1.0f) * di;
            #pragma unroll
            for (int j = 0; j < 8; ++j) { ax += ws[j] * (float)u[j][0]; ay += ws[j] * (float)u[j][1]; }
        }
        for (; e < n; ++e) {
            int s = sl[e];
            float ws = rsqrtf((float)cnt[s] + 1.0f) * di;
            half2v u = ((const half2v*)(tab + (size_t)s * 128))[lane];
            ax += ws * (float)u[0]; ay += ws * (float)u[1];
        }
        int c0 = half * 128 + lane * 2;
        float rx = fmaxf(ax + bias[c0], 0.0f);
        float ry = fmaxf(ay + bias[c0 + 1], 0.0f);
        ushort2 hv, lv;
        hv.x = f2bf(rx); lv.x = f2bf(rx - bf2f(hv.x));
        hv.y = f2bf(ry); lv.y = f2bf(ry - bf2f(hv.y));
        *(ushort2*)&oh[(size_t)d * 256 + c0] = hv;
        *(ushort2*)&ol[(size_t)d * 256 + c0] = lv;
    }
}

// ------- aggregation layer 1: table [NPAD][128] fp16; fp32 h1 out + split bf16 --------
__global__ __launch_bounds__(256) void agg128_bias_bf(const _Float16* __restrict__ hl,
                                                      const int* __restrict__ cnt,
                                                      const int* __restrict__ slots,
                                                      const float* __restrict__ bias,
                                                      float* __restrict__ out,
                                                      ushort_t* __restrict__ oh,
                                                      ushort_t* __restrict__ ol) {
    int d = blockIdx.x * 4 + (threadIdx.x >> 6);
    int lane = threadIdx.x & 63;
    int n = cnt[d];
    float di = rsqrtf((float)n + 1.0f);
    const int* sl = slots + (size_t)d * SLOT;
    half2v v = ((const half2v*)(hl + (size_t)d * 128))[lane];
    float w = di * di;
    float ax = w * (float)v[0], ay = w * (float)v[1];
    int e = 0;
    for (; e + 8 <= n; e += 8) {
        int s[8]; half2v u[8]; float ws[8];
        #pragma unroll
        for (int j = 0; j < 8; ++j) s[j] = sl[e + j];
        #pragma unroll
        for (int j = 0; j < 8; ++j) u[j] = ((const half2v*)(hl + (size_t)s[j] * 128))[lane];
        #pragma unroll
        for (int j = 0; j < 8; ++j) ws[j] = rsqrtf((float)cnt[s[j]] + 1.0f) * di;
        #pragma unroll
        for (int j = 0; j < 8; ++j) { ax += ws[j] * (float)u[j][0]; ay += ws[j] * (float)u[j][1]; }
    }
    for (; e < n; ++e) {
        int s = sl[e];
        float ws = rsqrtf((float)cnt[s] + 1.0f) * di;
        half2v u = ((const half2v*)(hl + (size_t)s * 128))[lane];
        ax += ws * (float)u[0]; ay += ws * (float)u[1];
    }
    int c0 = lane * 2;
    float rx = ax + bias[c0], ry = ay + bias[c0 + 1];      // no relu (last conv layer)
    ((float2*)(out + (size_t)d * 128))[lane] = make_float2(rx, ry);
    ushort2 hv, lv;
    hv.x = f2bf(rx); lv.x = f2bf(rx - bf2f(hv.x));
    hv.y = f2bf(ry); lv.y = f2bf(ry - bf2f(hv.y));
    *(ushort2*)&oh[(size_t)d * 128 + c0] = hv;
    *(ushort2*)&ol[(size_t)d * 128 + c0] = lv;
}

// ---------------- final merge of 391 per-block column maxima ----------------
__global__ __launch_bounds__(128) void k_reduce2(const float* __restrict__ pv,
                                                 const int* __restrict__ pi,
                                                 const float* __restrict__ Pb,
                                                 float* __restrict__ out) {
    int c = threadIdx.x;
    float best = -3.402823466e+38f;
    int bi = 0x7fffffff;
    for (int b = 0; b < MTILES; ++b) {
        float v = pv[b * 128 + c];
        int   i = pi[b * 128 + c];
        if (v > best || (v == best && i < bi)) { best = v; bi = i; }
    }
    out[(size_t)N_NODES * OUT_CH + c]       = best + Pb[c];   // max(p+Pb) = max(p)+Pb
    out[(size_t)N_NODES * OUT_CH + 128 + c] = (float)bi;
}

extern "C" void kernel_launch(void* const* d_in, const int* in_sizes, int n_in,
                              void* d_out, int out_size, void* d_ws, size_t ws_size,
                              hipStream_t stream) {
    const float* x  = (const float*)d_in[0];
    const int*   ei = (const int*)d_in[1];
    const float* W0 = (const float*)d_in[2];
    const float* b0 = (const float*)d_in[3];
    const float* W1 = (const float*)d_in[4];
    const float* b1 = (const float*)d_in[5];
    const float* PW = (const float*)d_in[6];
    const float* Pb = (const float*)d_in[7];
    float* out = (float*)d_out;
    const int* esrc = ei;
    const int* edst = ei + N_EDGES;

    char* w = (char*)d_ws;
    size_t off = 0;
    auto alloc = [&](size_t bytes) -> void* {
        void* p = (void*)(w + off);
        off = (off + bytes + 255) & ~(size_t)255;
        return p;
    };
    int*       cnt    = (int*)alloc((size_t)N_NODES * 4);
    int*       slots  = (int*)alloc((size_t)N_NODES * SLOT * 4);
    float*     pmax_v = (float*)alloc((size_t)MTILES * 128 * 4);
    int*       pmax_i = (int*)alloc((size_t)MTILES * 128 * 4);
    _Float16*  bufH   = (_Float16*)alloc((size_t)2 * NPAD * 128 * 2);    // hl0 halves / hl1
    ushort_t*  xh     = (ushort_t*)alloc((size_t)N_NODES * IN_CH * 2);
    ushort_t*  xl     = (ushort_t*)alloc((size_t)N_NODES * IN_CH * 2);
    ushort_t*  W0hT   = (ushort_t*)alloc((size_t)IN_CH * HID_CH * 2);
    ushort_t*  W0lT   = (ushort_t*)alloc((size_t)IN_CH * HID_CH * 2);
    ushort_t*  W1hT   = (ushort_t*)alloc((size_t)HID_CH * OUT_CH * 2);
    ushort_t*  W1lT   = (ushort_t*)alloc((size_t)HID_CH * OUT_CH * 2);
    ushort_t*  PWhT   = (ushort_t*)alloc((size_t)OUT_CH * OUT_CH * 2);
    ushort_t*  PWlT   = (ushort_t*)alloc((size_t)OUT_CH * OUT_CH * 2);
    // aliases: x-split space dead after GEMM0 -> h0/h1 split buffers
    ushort_t* h0h = xh;
    ushort_t* h0l = xl;
    ushort_t* h1h = xh + (size_t)N_NODES * HID_CH;
    ushort_t* h1l = xl + (size_t)N_NODES * HID_CH;

    // --- cnt zero (stream-ordered, graph-capturable) + mega prep ---
    hipMemsetAsync(cnt, 0, (size_t)N_NODES * 4, stream);
    k_prep<<<PB_E, 256, 0, stream>>>(x, W0, W1, PW, esrc, edst, xh, xl, cnt, slots,
                                     W0hT, W0lT, W1hT, W1lT, PWhT, PWlT);

    // --- layer 0: hl0 = x @ W0 (fp16, half-split table) ; h0 = relu(agg + b0) ---
    gemm_bf<_Float16, 1><<<dim3(2, MTILES), 256, 0, stream>>>(
        xh, xl, W0hT, W0lT, bufH, nullptr, nullptr, N_NODES, HID_CH, IN_CH);
    agg256_relu_bf<<<N_NODES / 4, 256, 0, stream>>>(bufH, cnt, slots, b0, h0h, h0l);

    // --- layer 1: hl1 = h0 @ W1 (fp16 table) ; h1 = agg + b1 -> d_out + split bf16 ---
    gemm_bf<_Float16, 0><<<dim3(1, MTILES), 256, 0, stream>>>(
        h0h, h0l, W1hT, W1lT, bufH, nullptr, nullptr, N_NODES, OUT_CH, HID_CH);
    agg128_bias_bf<<<N_NODES / 4, 256, 0, stream>>>(bufH, cnt, slots, b1, out, h1h, h1l);

    // --- PGE: p = h1 @ PW fused with column max/argmax ; final merge ---
    gemm_bf<float, 2><<<dim3(1, MTILES), 256, 0, stream>>>(
        h1h, h1l, PWhT, PWlT, (float*)nullptr, pmax_v, pmax_i, N_NODES, OUT_CH, OUT_CH);
    k_reduce2<<<1, 128, 0, stream>>>(pmax_v, pmax_i, Pb, out);

    (void)in_sizes; (void)n_in; (void)out_size; (void)ws_size;
}